// Round 1
// baseline (663.843 us; speedup 1.0000x reference)
//
#include <hip/hip_runtime.h>
#include <hip/hip_bf16.h>

#define B_ 64
#define S_ 512
#define H_ 1024
#define M_ 26
#define E_ 676

// ---------- prep: A = W1+W3, Bw = W2-W3 (W_ed = [W1;W2;W3], each H x H) ----------
__global__ void k_prep(const float* __restrict__ Wed, float* __restrict__ Aw,
                       float* __restrict__ Bw) {
    int i = blockIdx.x * 256 + threadIdx.x;          // grid covers H_*H_ exactly
    const int HH = H_ * H_;
    float w1 = Wed[i], w2 = Wed[HH + i], w3 = Wed[2 * HH + i];
    Aw[i] = w1 + w3;
    Bw[i] = w2 - w3;
}

// ---------- count[b] = #valid offsets ----------
__global__ void k_count(const int* __restrict__ off, int* __restrict__ count) {
    int b = threadIdx.x;                              // 64 threads
    int c = 0;
    for (int m = 0; m < M_ - 1; ++m) c += (off[b * (M_ - 1) + m] > 0) ? 1 : 0;
    count[b] = c;
}

// ---------- cls GEMM: naf = cls@W_naf + b_naf ; cdh = cls@W_cd + b_cd (pre-tanh) ----------
__global__ void k_cls(const float* __restrict__ seq,
                      const float* __restrict__ Wnaf, const float* __restrict__ bnaf,
                      const float* __restrict__ Wcd,  const float* __restrict__ bcd,
                      float* __restrict__ naf, float* __restrict__ cdh) {
    __shared__ float clsS[H_];
    int b = blockIdx.y;
    int tid = threadIdx.x;
    const float4* src = (const float4*)(seq + (size_t)b * S_ * H_);   // row t=0
    ((float4*)clsS)[tid] = src[tid];                                  // 256*4 = 1024
    __syncthreads();
    int col = blockIdx.x * 256 + tid;                                 // 0..2047
    const float* W = (col < H_) ? Wnaf : Wcd;
    int c = (col < H_) ? col : col - H_;
    float acc = 0.f;
#pragma unroll 4
    for (int k = 0; k < H_; ++k) acc += clsS[k] * W[(size_t)k * H_ + c];
    if (col < H_) naf[(size_t)b * H_ + c] = acc + bnaf[c];
    else          cdh[(size_t)b * H_ + c] = acc + bcd[c];
}

// ---------- cls logits: tanh(cdh) @ W_co + b_co ----------
__global__ void k_logits(const float* __restrict__ cdh, const float* __restrict__ Wco,
                         const float* __restrict__ bco, float* __restrict__ out) {
    int b = blockIdx.x, tid = threadIdx.x;
    float a0 = 0.f, a1 = 0.f;
    for (int h = tid; h < H_; h += 256) {
        float t = tanhf(cdh[(size_t)b * H_ + h]);
        a0 += t * Wco[h * 2 + 0];
        a1 += t * Wco[h * 2 + 1];
    }
    __shared__ float s0[256], s1[256];
    s0[tid] = a0; s1[tid] = a1; __syncthreads();
    for (int o = 128; o > 0; o >>= 1) {
        if (tid < o) { s0[tid] += s0[tid + o]; s1[tid] += s1[tid + o]; }
        __syncthreads();
    }
    if (tid == 0) { out[b * 2 + 0] = s0[0] + bco[0]; out[b * 2 + 1] = s1[0] + bco[1]; }
}

// ---------- segment sums (chunked over t, atomic accumulate) ----------
__global__ void k_seg(const float* __restrict__ seq, const int* __restrict__ off,
                      float* __restrict__ node_sum) {
    int b = blockIdx.y;
    int chunk = blockIdx.x;                            // 16 chunks x 32 t
    __shared__ int offs[M_ - 1];
    __shared__ int c_s, offmax_s;
    int tid = threadIdx.x;
    if (tid < M_ - 1) offs[tid] = off[b * (M_ - 1) + tid];
    __syncthreads();
    if (tid == 0) {
        int c = 0;
        while (c < M_ - 1 && offs[c] > 0) c++;
        c_s = c; offmax_s = (c > 0) ? offs[c - 1] : 0;
    }
    __syncthreads();
    int c = c_s, offmax = offmax_s;
    int t0 = chunk * 32;
    int ts = max(t0, 1), te = min(t0 + 31, offmax);
    if (ts > te) return;
    int m = 0;
    while (m < c && offs[m] < ts) m++;
    const float4* sq = (const float4*)(seq + (size_t)b * S_ * H_);
    float4 acc = make_float4(0, 0, 0, 0);
    for (int t = ts; t <= te; ++t) {
        if (offs[m] < t) {
            float* dst = node_sum + ((size_t)(b * M_ + m)) * H_ + tid * 4;
            atomicAdd(dst + 0, acc.x); atomicAdd(dst + 1, acc.y);
            atomicAdd(dst + 2, acc.z); atomicAdd(dst + 3, acc.w);
            acc = make_float4(0, 0, 0, 0);
            while (offs[m] < t) m++;
        }
        float4 v = sq[(size_t)t * (H_ / 4) + tid];
        acc.x += v.x; acc.y += v.y; acc.z += v.z; acc.w += v.w;
    }
    float* dst = node_sum + ((size_t)(b * M_ + m)) * H_ + tid * 4;
    atomicAdd(dst + 0, acc.x); atomicAdd(dst + 1, acc.y);
    atomicAdd(dst + 2, acc.z); atomicAdd(dst + 3, acc.w);
}

// ---------- finalize node_full (in place over node_sum): /len, *valid, +naf@count, zero row M-1 ----------
__global__ void k_finalize(float* __restrict__ node, const int* __restrict__ off,
                           const int* __restrict__ count, const float* __restrict__ naf) {
    int b = blockIdx.y, m = blockIdx.x, tid = threadIdx.x;
    int cnt = count[b];
    float4 v = make_float4(0, 0, 0, 0);
    float4* row = (float4*)(node + ((size_t)(b * M_ + m)) * H_);
    if (m < M_ - 1) {
        int o = off[b * (M_ - 1) + m];
        if (o > 0) {
            int prev = (m > 0) ? off[b * (M_ - 1) + m - 1] : 0;
            float inv = 1.0f / (float)max(o - prev, 1);
            float4 s = row[tid];
            v = make_float4(s.x * inv, s.y * inv, s.z * inv, s.w * inv);
        }
    }
    if (m == cnt) {
        float4 a = ((const float4*)(naf + (size_t)b * H_))[tid];
        v.x += a.x; v.y += a.y; v.z += a.z; v.w += a.w;
    }
    row[tid] = v;
}

// ---------- generic fp32 GEMM: C(MxN) = A(MxK) @ B(KxN), all row-major, exact tiles ----------
__global__ __launch_bounds__(256) void k_gemm(const float* __restrict__ A,
                                              const float* __restrict__ Bm,
                                              float* __restrict__ C,
                                              int Mx, int Nx, int Kx) {
    __shared__ float As[16][64];
    __shared__ float Bs[16][64];
    int tid = threadIdx.x;
    int row0 = blockIdx.y * 64, col0 = blockIdx.x * 64;
    int tx = tid % 16, ty = tid / 16;
    float c[4][4] = {};
    int la_row = tid / 4;            // 0..63
    int la_k4  = (tid % 4) * 4;      // 0,4,8,12
    int lb_k   = tid / 16;           // 0..15
    int lb_c4  = (tid % 16) * 4;     // 0..60
    for (int k0 = 0; k0 < Kx; k0 += 16) {
        float4 a = *(const float4*)(A + (size_t)(row0 + la_row) * Kx + k0 + la_k4);
        *(float4*)(&Bs[lb_k][lb_c4]) =
            *(const float4*)(Bm + (size_t)(k0 + lb_k) * Nx + col0 + lb_c4);
        As[la_k4 + 0][la_row] = a.x;
        As[la_k4 + 1][la_row] = a.y;
        As[la_k4 + 2][la_row] = a.z;
        As[la_k4 + 3][la_row] = a.w;
        __syncthreads();
#pragma unroll
        for (int kk = 0; kk < 16; ++kk) {
            float4 av = *(const float4*)(&As[kk][ty * 4]);
            float4 bv = *(const float4*)(&Bs[kk][tx * 4]);
            c[0][0] += av.x * bv.x; c[0][1] += av.x * bv.y; c[0][2] += av.x * bv.z; c[0][3] += av.x * bv.w;
            c[1][0] += av.y * bv.x; c[1][1] += av.y * bv.y; c[1][2] += av.y * bv.z; c[1][3] += av.y * bv.w;
            c[2][0] += av.z * bv.x; c[2][1] += av.z * bv.y; c[2][2] += av.z * bv.z; c[2][3] += av.z * bv.w;
            c[3][0] += av.w * bv.x; c[3][1] += av.w * bv.y; c[3][2] += av.w * bv.z; c[3][3] += av.w * bv.w;
        }
        __syncthreads();
    }
#pragma unroll
    for (int i = 0; i < 4; ++i)
#pragma unroll
        for (int j = 0; j < 4; ++j)
            C[(size_t)(row0 + ty * 4 + i) * Nx + col0 + tx * 4 + j] = c[i][j];
}

// ---------- node logits: tanh(ndh + b_nd) @ W_no + b_no, wave per row ----------
__global__ void k_node_logits(const float* __restrict__ ndh, const float* __restrict__ bnd,
                              const float* __restrict__ Wno, const float* __restrict__ bno,
                              float* __restrict__ out) {
    int r = blockIdx.x * 4 + (threadIdx.x >> 6);
    int lane = threadIdx.x & 63;
    const float* src = ndh + (size_t)r * H_;
    float a0 = 0.f, a1 = 0.f;
    for (int h = lane; h < H_; h += 64) {
        float t = tanhf(src[h] + bnd[h]);
        a0 += t * Wno[h * 2 + 0];
        a1 += t * Wno[h * 2 + 1];
    }
    for (int o = 32; o > 0; o >>= 1) { a0 += __shfl_down(a0, o); a1 += __shfl_down(a1, o); }
    if (lane == 0) { out[(size_t)r * 2 + 0] = a0 + bno[0]; out[(size_t)r * 2 + 1] = a1 + bno[1]; }
}

// ---------- edge logits: tanh(valid*(U[j]+V[i]) + b_ed) @ W_eo + b_eo, wave per edge ----------
__global__ void k_edge(const float* __restrict__ U, const float* __restrict__ V,
                       const int* __restrict__ count, const float* __restrict__ bed,
                       const float* __restrict__ Weo, const float* __restrict__ beo,
                       float* __restrict__ out) {
    int b = blockIdx.y;
    int k = blockIdx.x * 4 + (threadIdx.x >> 6);
    int lane = threadIdx.x & 63;
    int n = count[b] + 1;
    bool valid = k < n * n;                 // wave-uniform
    int i = 0, j = 0;
    if (valid) { i = k / n; j = k % n; }
    const float* Uj = U + ((size_t)(b * M_ + j)) * H_;
    const float* Vi = V + ((size_t)(b * M_ + i)) * H_;
    float a0 = 0.f, a1 = 0.f;
    for (int h = lane; h < H_; h += 64) {
        float s = bed[h];
        if (valid) s += Uj[h] + Vi[h];
        float t = tanhf(s);
        a0 += t * Weo[h * 2 + 0];
        a1 += t * Weo[h * 2 + 1];
    }
    for (int o = 32; o > 0; o >>= 1) { a0 += __shfl_down(a0, o); a1 += __shfl_down(a1, o); }
    if (lane == 0) {
        out[((size_t)b * E_ + k) * 2 + 0] = a0 + beo[0];
        out[((size_t)b * E_ + k) * 2 + 1] = a1 + beo[1];
    }
}

extern "C" void kernel_launch(void* const* d_in, const int* in_sizes, int n_in,
                              void* d_out, int out_size, void* d_ws, size_t ws_size,
                              hipStream_t stream) {
    const float* seq  = (const float*)d_in[0];
    const int*   off  = (const int*)d_in[1];
    // d_in[2] node_labels, d_in[3] edge_labels: only shapes used
    const float* Wnaf = (const float*)d_in[4];  const float* bnaf = (const float*)d_in[5];
    const float* Wcd  = (const float*)d_in[6];  const float* bcd  = (const float*)d_in[7];
    const float* Wco  = (const float*)d_in[8];  const float* bco  = (const float*)d_in[9];
    const float* Wnd  = (const float*)d_in[10]; const float* bnd  = (const float*)d_in[11];
    const float* Wno  = (const float*)d_in[12]; const float* bno  = (const float*)d_in[13];
    const float* Wed  = (const float*)d_in[14]; const float* bed  = (const float*)d_in[15];
    const float* Weo  = (const float*)d_in[16]; const float* beo  = (const float*)d_in[17];
    float* out = (float*)d_out;

    float* ws = (float*)d_ws;
    size_t p = 0;
    float* node = ws + p;  p += (size_t)B_ * M_ * H_;   // node_sum -> node_full (in place)
    float* naf  = ws + p;  p += (size_t)B_ * H_;
    float* cdh  = ws + p;  p += (size_t)B_ * H_;
    float* Aw   = ws + p;  p += (size_t)H_ * H_;
    float* Bw   = ws + p;  p += (size_t)H_ * H_;
    float* ndh  = ws + p;  p += (size_t)B_ * M_ * H_;
    float* U    = ws + p;  p += (size_t)B_ * M_ * H_;
    float* V    = ws + p;  p += (size_t)B_ * M_ * H_;
    int*   cnt  = (int*)(ws + p); p += 64;

    hipMemsetAsync(node, 0, (size_t)B_ * M_ * H_ * sizeof(float), stream);

    k_prep<<<dim3(H_ * H_ / 256), 256, 0, stream>>>(Wed, Aw, Bw);
    k_count<<<1, 64, 0, stream>>>(off, cnt);
    k_cls<<<dim3(8, B_), 256, 0, stream>>>(seq, Wnaf, bnaf, Wcd, bcd, naf, cdh);
    k_logits<<<B_, 256, 0, stream>>>(cdh, Wco, bco, out);
    k_seg<<<dim3(16, B_), 256, 0, stream>>>(seq, off, node);
    k_finalize<<<dim3(M_, B_), 256, 0, stream>>>(node, off, cnt, naf);
    k_gemm<<<dim3(H_ / 64, (B_ * M_) / 64), 256, 0, stream>>>(node, Wnd, ndh, B_ * M_, H_, H_);
    k_gemm<<<dim3(H_ / 64, (B_ * M_) / 64), 256, 0, stream>>>(node, Aw, U, B_ * M_, H_, H_);
    k_gemm<<<dim3(H_ / 64, (B_ * M_) / 64), 256, 0, stream>>>(node, Bw, V, B_ * M_, H_, H_);
    k_node_logits<<<(B_ * M_) / 4, 256, 0, stream>>>(ndh, bnd, Wno, bno, out + B_ * 2);
    k_edge<<<dim3(E_ / 4, B_), 256, 0, stream>>>(U, V, cnt, bed, Weo, beo,
                                                 out + B_ * 2 + B_ * M_ * 2);
}

// Round 2
// 569.642 us; speedup vs baseline: 1.1654x; 1.1654x over previous
//
#include <hip/hip_runtime.h>
#include <hip/hip_bf16.h>

#define B_ 64
#define S_ 512
#define H_ 1024
#define M_ 26
#define E_ 676

// ---------- prep: A = W1+W3, Bw = W2-W3 (W_ed = [W1;W2;W3], each H x H) ----------
__global__ void k_prep(const float* __restrict__ Wed, float* __restrict__ Aw,
                       float* __restrict__ Bw) {
    int i = blockIdx.x * 256 + threadIdx.x;          // grid covers H_*H_ exactly
    const int HH = H_ * H_;
    float w1 = Wed[i], w2 = Wed[HH + i], w3 = Wed[2 * HH + i];
    Aw[i] = w1 + w3;
    Bw[i] = w2 - w3;
}

// ---------- init: blocks 0..255 -> naf=bnaf, 256..511 -> cdh=bcd, block 512 -> count ----------
__global__ void k_init(const float* __restrict__ bnaf, const float* __restrict__ bcd,
                       float* __restrict__ naf, float* __restrict__ cdh,
                       const int* __restrict__ off, int* __restrict__ count) {
    int bx = blockIdx.x;
    if (bx < 256) {
        int i = bx * 256 + threadIdx.x;               // 0 .. 65535
        naf[i] = bnaf[i & (H_ - 1)];
    } else if (bx < 512) {
        int i = (bx - 256) * 256 + threadIdx.x;
        cdh[i] = bcd[i & (H_ - 1)];
    } else {
        if (threadIdx.x < 64) {
            int b = threadIdx.x;
            int c = 0;
            for (int m = 0; m < M_ - 1; ++m) c += (off[b * (M_ - 1) + m] > 0) ? 1 : 0;
            count[b] = c;
        }
    }
}

// ---------- cls GEMM, split-K tiled: [64 x 1024] @ [1024 x 2048] -> naf|cdh (atomic) ----------
__global__ __launch_bounds__(256) void k_cls2(const float* __restrict__ seq,
                                              const float* __restrict__ Wnaf,
                                              const float* __restrict__ Wcd,
                                              float* __restrict__ naf,
                                              float* __restrict__ cdh) {
    __shared__ float As[16][64];
    __shared__ float Bs[16][64];
    int tid = threadIdx.x;
    int bx = blockIdx.x;                 // 0..31 : 64-wide column tile of 2048
    int kbase = blockIdx.y * 128;        // 8 K-slices of 128
    const float* W;
    float* dst;
    int cbase;
    if (bx < 16) { W = Wnaf; dst = naf; cbase = bx * 64; }
    else         { W = Wcd;  dst = cdh; cbase = (bx - 16) * 64; }
    int tx = tid % 16, ty = tid / 16;
    float c[4][4] = {};
    int la_row = tid / 4;            // batch 0..63
    int la_k4  = (tid % 4) * 4;      // 0,4,8,12
    int lb_k   = tid / 16;           // 0..15
    int lb_c4  = (tid % 16) * 4;     // 0..60
    for (int k0 = 0; k0 < 128; k0 += 16) {
        float4 a = *(const float4*)(seq + (size_t)la_row * S_ * H_ + kbase + k0 + la_k4);
        *(float4*)(&Bs[lb_k][lb_c4]) =
            *(const float4*)(W + (size_t)(kbase + k0 + lb_k) * H_ + cbase + lb_c4);
        As[la_k4 + 0][la_row] = a.x;
        As[la_k4 + 1][la_row] = a.y;
        As[la_k4 + 2][la_row] = a.z;
        As[la_k4 + 3][la_row] = a.w;
        __syncthreads();
#pragma unroll
        for (int kk = 0; kk < 16; ++kk) {
            float4 av = *(const float4*)(&As[kk][ty * 4]);
            float4 bv = *(const float4*)(&Bs[kk][tx * 4]);
            c[0][0] += av.x * bv.x; c[0][1] += av.x * bv.y; c[0][2] += av.x * bv.z; c[0][3] += av.x * bv.w;
            c[1][0] += av.y * bv.x; c[1][1] += av.y * bv.y; c[1][2] += av.y * bv.z; c[1][3] += av.y * bv.w;
            c[2][0] += av.z * bv.x; c[2][1] += av.z * bv.y; c[2][2] += av.z * bv.z; c[2][3] += av.z * bv.w;
            c[3][0] += av.w * bv.x; c[3][1] += av.w * bv.y; c[3][2] += av.w * bv.z; c[3][3] += av.w * bv.w;
        }
        __syncthreads();
    }
#pragma unroll
    for (int i = 0; i < 4; ++i)
#pragma unroll
        for (int j = 0; j < 4; ++j)
            atomicAdd(dst + (size_t)(ty * 4 + i) * H_ + cbase + tx * 4 + j, c[i][j]);
}

// ---------- cls logits: tanh(cdh) @ W_co + b_co ----------
__global__ void k_logits(const float* __restrict__ cdh, const float* __restrict__ Wco,
                         const float* __restrict__ bco, float* __restrict__ out) {
    int b = blockIdx.x, tid = threadIdx.x;
    float a0 = 0.f, a1 = 0.f;
    for (int h = tid; h < H_; h += 256) {
        float t = tanhf(cdh[(size_t)b * H_ + h]);
        a0 += t * Wco[h * 2 + 0];
        a1 += t * Wco[h * 2 + 1];
    }
    __shared__ float s0[256], s1[256];
    s0[tid] = a0; s1[tid] = a1; __syncthreads();
    for (int o = 128; o > 0; o >>= 1) {
        if (tid < o) { s0[tid] += s0[tid + o]; s1[tid] += s1[tid + o]; }
        __syncthreads();
    }
    if (tid == 0) { out[b * 2 + 0] = s0[0] + bco[0]; out[b * 2 + 1] = s1[0] + bco[1]; }
}

// ---------- segment sums (chunked over t, atomic accumulate) ----------
__global__ void k_seg(const float* __restrict__ seq, const int* __restrict__ off,
                      float* __restrict__ node_sum) {
    int b = blockIdx.y;
    int chunk = blockIdx.x;                            // 16 chunks x 32 t
    __shared__ int offs[M_ - 1];
    __shared__ int c_s, offmax_s;
    int tid = threadIdx.x;
    if (tid < M_ - 1) offs[tid] = off[b * (M_ - 1) + tid];
    __syncthreads();
    if (tid == 0) {
        int c = 0;
        while (c < M_ - 1 && offs[c] > 0) c++;
        c_s = c; offmax_s = (c > 0) ? offs[c - 1] : 0;
    }
    __syncthreads();
    int c = c_s, offmax = offmax_s;
    int t0 = chunk * 32;
    int ts = max(t0, 1), te = min(t0 + 31, offmax);
    if (ts > te) return;
    int m = 0;
    while (m < c && offs[m] < ts) m++;
    const float4* sq = (const float4*)(seq + (size_t)b * S_ * H_);
    float4 acc = make_float4(0, 0, 0, 0);
    for (int t = ts; t <= te; ++t) {
        if (offs[m] < t) {
            float* dst = node_sum + ((size_t)(b * M_ + m)) * H_ + tid * 4;
            atomicAdd(dst + 0, acc.x); atomicAdd(dst + 1, acc.y);
            atomicAdd(dst + 2, acc.z); atomicAdd(dst + 3, acc.w);
            acc = make_float4(0, 0, 0, 0);
            while (offs[m] < t) m++;
        }
        float4 v = sq[(size_t)t * (H_ / 4) + tid];
        acc.x += v.x; acc.y += v.y; acc.z += v.z; acc.w += v.w;
    }
    float* dst = node_sum + ((size_t)(b * M_ + m)) * H_ + tid * 4;
    atomicAdd(dst + 0, acc.x); atomicAdd(dst + 1, acc.y);
    atomicAdd(dst + 2, acc.z); atomicAdd(dst + 3, acc.w);
}

// ---------- finalize node_full (in place): /len, *valid, +naf@count, zero row M-1 ----------
__global__ void k_finalize(float* __restrict__ node, const int* __restrict__ off,
                           const int* __restrict__ count, const float* __restrict__ naf) {
    int b = blockIdx.y, m = blockIdx.x, tid = threadIdx.x;
    int cnt = count[b];
    float4 v = make_float4(0, 0, 0, 0);
    float4* row = (float4*)(node + ((size_t)(b * M_ + m)) * H_);
    if (m < M_ - 1) {
        int o = off[b * (M_ - 1) + m];
        if (o > 0) {
            int prev = (m > 0) ? off[b * (M_ - 1) + m - 1] : 0;
            float inv = 1.0f / (float)max(o - prev, 1);
            float4 s = row[tid];
            v = make_float4(s.x * inv, s.y * inv, s.z * inv, s.w * inv);
        }
    }
    if (m == cnt) {
        float4 a = ((const float4*)(naf + (size_t)b * H_))[tid];
        v.x += a.x; v.y += a.y; v.z += a.z; v.w += a.w;
    }
    row[tid] = v;
}

// ---------- generic fp32 GEMM: C(MxN) = A(MxK) @ B(KxN), all row-major, exact tiles ----------
__global__ __launch_bounds__(256) void k_gemm(const float* __restrict__ A,
                                              const float* __restrict__ Bm,
                                              float* __restrict__ C,
                                              int Mx, int Nx, int Kx) {
    __shared__ float As[16][64];
    __shared__ float Bs[16][64];
    int tid = threadIdx.x;
    int row0 = blockIdx.y * 64, col0 = blockIdx.x * 64;
    int tx = tid % 16, ty = tid / 16;
    float c[4][4] = {};
    int la_row = tid / 4;            // 0..63
    int la_k4  = (tid % 4) * 4;      // 0,4,8,12
    int lb_k   = tid / 16;           // 0..15
    int lb_c4  = (tid % 16) * 4;     // 0..60
    for (int k0 = 0; k0 < Kx; k0 += 16) {
        float4 a = *(const float4*)(A + (size_t)(row0 + la_row) * Kx + k0 + la_k4);
        *(float4*)(&Bs[lb_k][lb_c4]) =
            *(const float4*)(Bm + (size_t)(k0 + lb_k) * Nx + col0 + lb_c4);
        As[la_k4 + 0][la_row] = a.x;
        As[la_k4 + 1][la_row] = a.y;
        As[la_k4 + 2][la_row] = a.z;
        As[la_k4 + 3][la_row] = a.w;
        __syncthreads();
#pragma unroll
        for (int kk = 0; kk < 16; ++kk) {
            float4 av = *(const float4*)(&As[kk][ty * 4]);
            float4 bv = *(const float4*)(&Bs[kk][tx * 4]);
            c[0][0] += av.x * bv.x; c[0][1] += av.x * bv.y; c[0][2] += av.x * bv.z; c[0][3] += av.x * bv.w;
            c[1][0] += av.y * bv.x; c[1][1] += av.y * bv.y; c[1][2] += av.y * bv.z; c[1][3] += av.y * bv.w;
            c[2][0] += av.z * bv.x; c[2][1] += av.z * bv.y; c[2][2] += av.z * bv.z; c[2][3] += av.z * bv.w;
            c[3][0] += av.w * bv.x; c[3][1] += av.w * bv.y; c[3][2] += av.w * bv.z; c[3][3] += av.w * bv.w;
        }
        __syncthreads();
    }
#pragma unroll
    for (int i = 0; i < 4; ++i)
#pragma unroll
        for (int j = 0; j < 4; ++j)
            C[(size_t)(row0 + ty * 4 + i) * Nx + col0 + tx * 4 + j] = c[i][j];
}

// ---------- node logits: tanh(ndh + b_nd) @ W_no + b_no, wave per row ----------
__global__ void k_node_logits(const float* __restrict__ ndh, const float* __restrict__ bnd,
                              const float* __restrict__ Wno, const float* __restrict__ bno,
                              float* __restrict__ out) {
    int r = blockIdx.x * 4 + (threadIdx.x >> 6);
    int lane = threadIdx.x & 63;
    const float* src = ndh + (size_t)r * H_;
    float a0 = 0.f, a1 = 0.f;
    for (int h = lane; h < H_; h += 64) {
        float t = tanhf(src[h] + bnd[h]);
        a0 += t * Wno[h * 2 + 0];
        a1 += t * Wno[h * 2 + 1];
    }
    for (int o = 32; o > 0; o >>= 1) { a0 += __shfl_down(a0, o); a1 += __shfl_down(a1, o); }
    if (lane == 0) { out[(size_t)r * 2 + 0] = a0 + bno[0]; out[(size_t)r * 2 + 1] = a1 + bno[1]; }
}

// ---------- edge logits: tanh(valid*(U[j]+V[i]) + b_ed) @ W_eo + b_eo, wave per edge ----------
__global__ void k_edge(const float* __restrict__ U, const float* __restrict__ V,
                       const int* __restrict__ count, const float* __restrict__ bed,
                       const float* __restrict__ Weo, const float* __restrict__ beo,
                       float* __restrict__ out) {
    int b = blockIdx.y;
    int k = blockIdx.x * 4 + (threadIdx.x >> 6);
    int lane = threadIdx.x & 63;
    int n = count[b] + 1;
    bool valid = k < n * n;                 // wave-uniform
    int i = 0, j = 0;
    if (valid) { i = k / n; j = k % n; }
    const float* Uj = U + ((size_t)(b * M_ + j)) * H_;
    const float* Vi = V + ((size_t)(b * M_ + i)) * H_;
    float a0 = 0.f, a1 = 0.f;
    for (int h = lane; h < H_; h += 64) {
        float s = bed[h];
        if (valid) s += Uj[h] + Vi[h];
        float t = tanhf(s);
        a0 += t * Weo[h * 2 + 0];
        a1 += t * Weo[h * 2 + 1];
    }
    for (int o = 32; o > 0; o >>= 1) { a0 += __shfl_down(a0, o); a1 += __shfl_down(a1, o); }
    if (lane == 0) {
        out[((size_t)b * E_ + k) * 2 + 0] = a0 + beo[0];
        out[((size_t)b * E_ + k) * 2 + 1] = a1 + beo[1];
    }
}

extern "C" void kernel_launch(void* const* d_in, const int* in_sizes, int n_in,
                              void* d_out, int out_size, void* d_ws, size_t ws_size,
                              hipStream_t stream) {
    const float* seq  = (const float*)d_in[0];
    const int*   off  = (const int*)d_in[1];
    const float* Wnaf = (const float*)d_in[4];  const float* bnaf = (const float*)d_in[5];
    const float* Wcd  = (const float*)d_in[6];  const float* bcd  = (const float*)d_in[7];
    const float* Wco  = (const float*)d_in[8];  const float* bco  = (const float*)d_in[9];
    const float* Wnd  = (const float*)d_in[10]; const float* bnd  = (const float*)d_in[11];
    const float* Wno  = (const float*)d_in[12]; const float* bno  = (const float*)d_in[13];
    const float* Wed  = (const float*)d_in[14]; const float* bed  = (const float*)d_in[15];
    const float* Weo  = (const float*)d_in[16]; const float* beo  = (const float*)d_in[17];
    float* out = (float*)d_out;

    float* ws = (float*)d_ws;
    size_t p = 0;
    float* node = ws + p;  p += (size_t)B_ * M_ * H_;   // node_sum -> node_full (in place)
    float* naf  = ws + p;  p += (size_t)B_ * H_;
    float* cdh  = ws + p;  p += (size_t)B_ * H_;
    float* Aw   = ws + p;  p += (size_t)H_ * H_;
    float* Bw   = ws + p;  p += (size_t)H_ * H_;
    float* ndh  = ws + p;  p += (size_t)B_ * M_ * H_;
    float* U    = ws + p;  p += (size_t)B_ * M_ * H_;
    float* V    = ws + p;  p += (size_t)B_ * M_ * H_;
    int*   cnt  = (int*)(ws + p); p += 64;

    hipMemsetAsync(node, 0, (size_t)B_ * M_ * H_ * sizeof(float), stream);

    k_prep<<<dim3(H_ * H_ / 256), 256, 0, stream>>>(Wed, Aw, Bw);
    k_init<<<dim3(513), 256, 0, stream>>>(bnaf, bcd, naf, cdh, off, cnt);
    k_cls2<<<dim3(32, 8), 256, 0, stream>>>(seq, Wnaf, Wcd, naf, cdh);
    k_logits<<<B_, 256, 0, stream>>>(cdh, Wco, bco, out);
    k_seg<<<dim3(16, B_), 256, 0, stream>>>(seq, off, node);
    k_finalize<<<dim3(M_, B_), 256, 0, stream>>>(node, off, cnt, naf);
    k_gemm<<<dim3(H_ / 64, (B_ * M_) / 64), 256, 0, stream>>>(node, Wnd, ndh, B_ * M_, H_, H_);
    k_gemm<<<dim3(H_ / 64, (B_ * M_) / 64), 256, 0, stream>>>(node, Aw, U, B_ * M_, H_, H_);
    k_gemm<<<dim3(H_ / 64, (B_ * M_) / 64), 256, 0, stream>>>(node, Bw, V, B_ * M_, H_, H_);
    k_node_logits<<<(B_ * M_) / 4, 256, 0, stream>>>(ndh, bnd, Wno, bno, out + B_ * 2);
    k_edge<<<dim3(E_ / 4, B_), 256, 0, stream>>>(U, V, cnt, bed, Weo, beo,
                                                 out + B_ * 2 + B_ * M_ * 2);
}

// Round 3
// 397.150 us; speedup vs baseline: 1.6715x; 1.4343x over previous
//
#include <hip/hip_runtime.h>
#include <hip/hip_bf16.h>

#define B_ 64
#define S_ 512
#define H_ 1024
#define M_ 26
#define E_ 676

typedef short bf16x8 __attribute__((ext_vector_type(8)));
typedef float f32x4 __attribute__((ext_vector_type(4)));

__device__ __forceinline__ void gload16(const void* g, void* l) {
    __builtin_amdgcn_global_load_lds((const __attribute__((address_space(1))) unsigned int*)g,
                                     (__attribute__((address_space(3))) unsigned int*)l,
                                     16, 0, 0);
}

// ---------- prep: build Wt (3072 x 1024, bf16) = transposed [Wnd ; W1+W3 ; W2-W3] ----------
__global__ void k_prep(const float* __restrict__ Wnd, const float* __restrict__ Wed,
                       __hip_bfloat16* __restrict__ Wt) {
    __shared__ float T[32][33];
    int bx = blockIdx.x, by = blockIdx.y, s = blockIdx.z;
    int t = threadIdx.x;
    int c = t & 31, r0 = t >> 5;
    const int HH = H_ * H_;
#pragma unroll
    for (int i = 0; i < 4; ++i) {
        int r = r0 + 8 * i;                       // k within tile
        size_t k = by * 32 + r, n = bx * 32 + c;
        float v;
        if (s == 0)      v = Wnd[k * H_ + n];
        else if (s == 1) v = Wed[k * H_ + n] + Wed[2 * HH + k * H_ + n];
        else             v = Wed[HH + k * H_ + n] - Wed[2 * HH + k * H_ + n];
        T[r][c] = v;
    }
    __syncthreads();
#pragma unroll
    for (int i = 0; i < 4; ++i) {
        int rr = r0 + 8 * i;                      // n within tile
        Wt[(size_t)(s * H_ + bx * 32 + rr) * H_ + by * 32 + c] = __float2bfloat16(T[c][rr]);
    }
}

// ---------- init: naf=bnaf, cdh=bcd, count ----------
__global__ void k_init(const float* __restrict__ bnaf, const float* __restrict__ bcd,
                       float* __restrict__ naf, float* __restrict__ cdh,
                       const int* __restrict__ off, int* __restrict__ count) {
    int bx = blockIdx.x;
    if (bx < 256) {
        int i = bx * 256 + threadIdx.x;
        naf[i] = bnaf[i & (H_ - 1)];
    } else if (bx < 512) {
        int i = (bx - 256) * 256 + threadIdx.x;
        cdh[i] = bcd[i & (H_ - 1)];
    } else {
        if (threadIdx.x < 64) {
            int b = threadIdx.x;
            int c = 0;
            for (int m = 0; m < M_ - 1; ++m) c += (off[b * (M_ - 1) + m] > 0) ? 1 : 0;
            count[b] = c;
        }
    }
}

// ---------- cls GEMM, split-K tiled: [64 x 1024] @ [1024 x 2048] -> naf|cdh (atomic) ----------
__global__ __launch_bounds__(256) void k_cls2(const float* __restrict__ seq,
                                              const float* __restrict__ Wnaf,
                                              const float* __restrict__ Wcd,
                                              float* __restrict__ naf,
                                              float* __restrict__ cdh) {
    __shared__ float As[16][64];
    __shared__ float Bs[16][64];
    int tid = threadIdx.x;
    int bx = blockIdx.x;
    int kbase = blockIdx.y * 128;
    const float* W;
    float* dst;
    int cbase;
    if (bx < 16) { W = Wnaf; dst = naf; cbase = bx * 64; }
    else         { W = Wcd;  dst = cdh; cbase = (bx - 16) * 64; }
    int tx = tid % 16, ty = tid / 16;
    float c[4][4] = {};
    int la_row = tid / 4;
    int la_k4  = (tid % 4) * 4;
    int lb_k   = tid / 16;
    int lb_c4  = (tid % 16) * 4;
    for (int k0 = 0; k0 < 128; k0 += 16) {
        float4 a = *(const float4*)(seq + (size_t)la_row * S_ * H_ + kbase + k0 + la_k4);
        *(float4*)(&Bs[lb_k][lb_c4]) =
            *(const float4*)(W + (size_t)(kbase + k0 + lb_k) * H_ + cbase + lb_c4);
        As[la_k4 + 0][la_row] = a.x;
        As[la_k4 + 1][la_row] = a.y;
        As[la_k4 + 2][la_row] = a.z;
        As[la_k4 + 3][la_row] = a.w;
        __syncthreads();
#pragma unroll
        for (int kk = 0; kk < 16; ++kk) {
            float4 av = *(const float4*)(&As[kk][ty * 4]);
            float4 bv = *(const float4*)(&Bs[kk][tx * 4]);
            c[0][0] += av.x * bv.x; c[0][1] += av.x * bv.y; c[0][2] += av.x * bv.z; c[0][3] += av.x * bv.w;
            c[1][0] += av.y * bv.x; c[1][1] += av.y * bv.y; c[1][2] += av.y * bv.z; c[1][3] += av.y * bv.w;
            c[2][0] += av.z * bv.x; c[2][1] += av.z * bv.y; c[2][2] += av.z * bv.z; c[2][3] += av.z * bv.w;
            c[3][0] += av.w * bv.x; c[3][1] += av.w * bv.y; c[3][2] += av.w * bv.z; c[3][3] += av.w * bv.w;
        }
        __syncthreads();
    }
#pragma unroll
    for (int i = 0; i < 4; ++i)
#pragma unroll
        for (int j = 0; j < 4; ++j)
            atomicAdd(dst + (size_t)(ty * 4 + i) * H_ + cbase + tx * 4 + j, c[i][j]);
}

// ---------- cls logits ----------
__global__ void k_logits(const float* __restrict__ cdh, const float* __restrict__ Wco,
                         const float* __restrict__ bco, float* __restrict__ out) {
    int b = blockIdx.x, tid = threadIdx.x;
    float a0 = 0.f, a1 = 0.f;
    for (int h = tid; h < H_; h += 256) {
        float t = tanhf(cdh[(size_t)b * H_ + h]);
        a0 += t * Wco[h * 2 + 0];
        a1 += t * Wco[h * 2 + 1];
    }
    __shared__ float s0[256], s1[256];
    s0[tid] = a0; s1[tid] = a1; __syncthreads();
    for (int o = 128; o > 0; o >>= 1) {
        if (tid < o) { s0[tid] += s0[tid + o]; s1[tid] += s1[tid + o]; }
        __syncthreads();
    }
    if (tid == 0) { out[b * 2 + 0] = s0[0] + bco[0]; out[b * 2 + 1] = s1[0] + bco[1]; }
}

// ---------- segment sums ----------
__global__ void k_seg(const float* __restrict__ seq, const int* __restrict__ off,
                      float* __restrict__ node_sum) {
    int b = blockIdx.y;
    int chunk = blockIdx.x;
    __shared__ int offs[M_ - 1];
    __shared__ int c_s, offmax_s;
    int tid = threadIdx.x;
    if (tid < M_ - 1) offs[tid] = off[b * (M_ - 1) + tid];
    __syncthreads();
    if (tid == 0) {
        int c = 0;
        while (c < M_ - 1 && offs[c] > 0) c++;
        c_s = c; offmax_s = (c > 0) ? offs[c - 1] : 0;
    }
    __syncthreads();
    int c = c_s, offmax = offmax_s;
    int t0 = chunk * 32;
    int ts = max(t0, 1), te = min(t0 + 31, offmax);
    if (ts > te) return;
    int m = 0;
    while (m < c && offs[m] < ts) m++;
    const float4* sq = (const float4*)(seq + (size_t)b * S_ * H_);
    float4 acc = make_float4(0, 0, 0, 0);
    for (int t = ts; t <= te; ++t) {
        if (offs[m] < t) {
            float* dst = node_sum + ((size_t)(b * M_ + m)) * H_ + tid * 4;
            atomicAdd(dst + 0, acc.x); atomicAdd(dst + 1, acc.y);
            atomicAdd(dst + 2, acc.z); atomicAdd(dst + 3, acc.w);
            acc = make_float4(0, 0, 0, 0);
            while (offs[m] < t) m++;
        }
        float4 v = sq[(size_t)t * (H_ / 4) + tid];
        acc.x += v.x; acc.y += v.y; acc.z += v.z; acc.w += v.w;
    }
    float* dst = node_sum + ((size_t)(b * M_ + m)) * H_ + tid * 4;
    atomicAdd(dst + 0, acc.x); atomicAdd(dst + 1, acc.y);
    atomicAdd(dst + 2, acc.z); atomicAdd(dst + 3, acc.w);
}

// ---------- finalize -> bf16 node matrix ----------
__global__ void k_finalize(const float* __restrict__ sums, const int* __restrict__ off,
                           const int* __restrict__ count, const float* __restrict__ naf,
                           __hip_bfloat16* __restrict__ nodeB) {
    int b = blockIdx.y, m = blockIdx.x, tid = threadIdx.x;
    int cnt = count[b];
    float4 v = make_float4(0, 0, 0, 0);
    const float4* row = (const float4*)(sums + ((size_t)(b * M_ + m)) * H_);
    if (m < M_ - 1) {
        int o = off[b * (M_ - 1) + m];
        if (o > 0) {
            int prev = (m > 0) ? off[b * (M_ - 1) + m - 1] : 0;
            float inv = 1.0f / (float)max(o - prev, 1);
            float4 s = row[tid];
            v = make_float4(s.x * inv, s.y * inv, s.z * inv, s.w * inv);
        }
    }
    if (m == cnt) {
        float4 a = ((const float4*)(naf + (size_t)b * H_))[tid];
        v.x += a.x; v.y += a.y; v.z += a.z; v.w += a.w;
    }
    __hip_bfloat16 __attribute__((aligned(8))) h[4] = {
        __float2bfloat16(v.x), __float2bfloat16(v.y),
        __float2bfloat16(v.z), __float2bfloat16(v.w)};
    *(ushort4*)(nodeB + ((size_t)(b * M_ + m)) * H_ + tid * 4) = *(const ushort4*)h;
}

// ---------- MFMA GEMM: C(1664x3072) = nodeB(1664x1024) @ Wt^T, Wt is (3072x1024) ----------
#define GM 1664
#define GN 3072
#define GK 1024
__global__ __launch_bounds__(256) void k_mfma(const __hip_bfloat16* __restrict__ A,
                                              const __hip_bfloat16* __restrict__ Bt,
                                              float* __restrict__ C) {
    __shared__ __hip_bfloat16 As[128 * 32];
    __shared__ __hip_bfloat16 Bs[128 * 32];
    int tid = threadIdx.x;
    int wid = tid >> 6, ln = tid & 63;
    int row0 = blockIdx.y * 128, col0 = blockIdx.x * 128;
    // staging: per-lane global addr, wave-uniform LDS base (+lane*16B implicit)
    const __hip_bfloat16* ga = A + (size_t)(row0 + wid * 16 + (ln >> 2)) * GK + (ln & 3) * 8;
    const __hip_bfloat16* gb = Bt + (size_t)(col0 + wid * 16 + (ln >> 2)) * GK + (ln & 3) * 8;
    __hip_bfloat16* lA = As + wid * 512;     // bytes: wid*1024
    __hip_bfloat16* lB = Bs + wid * 512;
    int mrow = (wid >> 1) * 64, ncol = (wid & 1) * 64;
    int l15 = ln & 15, l4 = ln >> 4;
    f32x4 acc[4][4] = {};
    const __hip_bfloat16* pa = As + (size_t)(mrow + l15) * 32 + l4 * 8;
    const __hip_bfloat16* pb = Bs + (size_t)(ncol + l15) * 32 + l4 * 8;
    for (int k0 = 0; k0 < GK; k0 += 32) {
        gload16(ga, lA);
        gload16(ga + 64 * GK, lA + 2048);
        gload16(gb, lB);
        gload16(gb + 64 * GK, lB + 2048);
        ga += 32; gb += 32;
        __syncthreads();
        bf16x8 af[4], bf[4];
#pragma unroll
        for (int mi = 0; mi < 4; ++mi) af[mi] = *(const bf16x8*)(pa + mi * 16 * 32);
#pragma unroll
        for (int ni = 0; ni < 4; ++ni) bf[ni] = *(const bf16x8*)(pb + ni * 16 * 32);
#pragma unroll
        for (int mi = 0; mi < 4; ++mi)
#pragma unroll
            for (int ni = 0; ni < 4; ++ni)
                acc[mi][ni] = __builtin_amdgcn_mfma_f32_16x16x32_bf16(af[mi], bf[ni],
                                                                      acc[mi][ni], 0, 0, 0);
        __syncthreads();
    }
#pragma unroll
    for (int mi = 0; mi < 4; ++mi)
#pragma unroll
        for (int ni = 0; ni < 4; ++ni) {
            f32x4 v = acc[mi][ni];
            size_t r = row0 + mrow + mi * 16 + l4 * 4;
            size_t cc = col0 + ncol + ni * 16 + l15;
            C[(r + 0) * GN + cc] = v[0];
            C[(r + 1) * GN + cc] = v[1];
            C[(r + 2) * GN + cc] = v[2];
            C[(r + 3) * GN + cc] = v[3];
        }
}

// ---------- node logits: tanh(C[:, :1024] + b_nd) @ W_no + b_no ----------
__global__ void k_node_logits(const float* __restrict__ Cm, const float* __restrict__ bnd,
                              const float* __restrict__ Wno, const float* __restrict__ bno,
                              float* __restrict__ out) {
    int r = blockIdx.x * 4 + (threadIdx.x >> 6);
    int lane = threadIdx.x & 63;
    const float* src = Cm + (size_t)r * GN;
    float a0 = 0.f, a1 = 0.f;
    for (int h = lane; h < H_; h += 64) {
        float t = tanhf(src[h] + bnd[h]);
        a0 += t * Wno[h * 2 + 0];
        a1 += t * Wno[h * 2 + 1];
    }
    for (int o = 32; o > 0; o >>= 1) { a0 += __shfl_down(a0, o); a1 += __shfl_down(a1, o); }
    if (lane == 0) { out[(size_t)r * 2 + 0] = a0 + bno[0]; out[(size_t)r * 2 + 1] = a1 + bno[1]; }
}

// ---------- edge logits: tanh(U[j]+V[i]+b_ed) @ W_eo + b_eo ----------
__global__ void k_edge(const float* __restrict__ Cm, const int* __restrict__ count,
                       const float* __restrict__ bed, const float* __restrict__ Weo,
                       const float* __restrict__ beo, float* __restrict__ out) {
    int b = blockIdx.y;
    int k = blockIdx.x * 4 + (threadIdx.x >> 6);
    int lane = threadIdx.x & 63;
    int n = count[b] + 1;
    bool valid = k < n * n;
    int i = 0, j = 0;
    if (valid) { i = k / n; j = k % n; }
    const float* Uj = Cm + (size_t)(b * M_ + j) * GN + H_;
    const float* Vi = Cm + (size_t)(b * M_ + i) * GN + 2 * H_;
    float a0 = 0.f, a1 = 0.f;
    for (int h = lane; h < H_; h += 64) {
        float s = bed[h];
        if (valid) s += Uj[h] + Vi[h];
        float t = tanhf(s);
        a0 += t * Weo[h * 2 + 0];
        a1 += t * Weo[h * 2 + 1];
    }
    for (int o = 32; o > 0; o >>= 1) { a0 += __shfl_down(a0, o); a1 += __shfl_down(a1, o); }
    if (lane == 0) {
        out[((size_t)b * E_ + k) * 2 + 0] = a0 + beo[0];
        out[((size_t)b * E_ + k) * 2 + 1] = a1 + beo[1];
    }
}

extern "C" void kernel_launch(void* const* d_in, const int* in_sizes, int n_in,
                              void* d_out, int out_size, void* d_ws, size_t ws_size,
                              hipStream_t stream) {
    const float* seq  = (const float*)d_in[0];
    const int*   off  = (const int*)d_in[1];
    const float* Wnaf = (const float*)d_in[4];  const float* bnaf = (const float*)d_in[5];
    const float* Wcd  = (const float*)d_in[6];  const float* bcd  = (const float*)d_in[7];
    const float* Wco  = (const float*)d_in[8];  const float* bco  = (const float*)d_in[9];
    const float* Wnd  = (const float*)d_in[10]; const float* bnd  = (const float*)d_in[11];
    const float* Wno  = (const float*)d_in[12]; const float* bno  = (const float*)d_in[13];
    const float* Wed  = (const float*)d_in[14]; const float* bed  = (const float*)d_in[15];
    const float* Weo  = (const float*)d_in[16]; const float* beo  = (const float*)d_in[17];
    float* out = (float*)d_out;

    float* ws = (float*)d_ws;
    size_t p = 0;
    float* nodeS = ws + p;  p += (size_t)B_ * M_ * H_;           // fp32 segment sums
    float* naf   = ws + p;  p += (size_t)B_ * H_;
    float* cdh   = ws + p;  p += (size_t)B_ * H_;
    __hip_bfloat16* nodeB = (__hip_bfloat16*)(ws + p); p += (size_t)B_ * M_ * H_ / 2;
    __hip_bfloat16* Wt    = (__hip_bfloat16*)(ws + p); p += (size_t)3 * H_ * H_ / 2;
    float* Cbuf  = ws + p;  p += (size_t)B_ * M_ * 3 * H_;       // 1664 x 3072
    int*   cnt   = (int*)(ws + p); p += 64;

    hipMemsetAsync(nodeS, 0, (size_t)B_ * M_ * H_ * sizeof(float), stream);

    k_prep<<<dim3(32, 32, 3), 256, 0, stream>>>(Wnd, Wed, Wt);
    k_init<<<dim3(513), 256, 0, stream>>>(bnaf, bcd, naf, cdh, off, cnt);
    k_cls2<<<dim3(32, 8), 256, 0, stream>>>(seq, Wnaf, Wcd, naf, cdh);
    k_logits<<<B_, 256, 0, stream>>>(cdh, Wco, bco, out);
    k_seg<<<dim3(16, B_), 256, 0, stream>>>(seq, off, nodeS);
    k_finalize<<<dim3(M_, B_), 256, 0, stream>>>(nodeS, off, cnt, naf, nodeB);
    k_mfma<<<dim3(GN / 128, GM / 128), 256, 0, stream>>>(nodeB, Wt, Cbuf);
    k_node_logits<<<(B_ * M_) / 4, 256, 0, stream>>>(Cbuf, bnd, Wno, bno, out + B_ * 2);
    k_edge<<<dim3(E_ / 4, B_), 256, 0, stream>>>(Cbuf, cnt, bed, Weo, beo,
                                                 out + B_ * 2 + B_ * M_ * 2);
}

// Round 4
// 344.567 us; speedup vs baseline: 1.9266x; 1.1526x over previous
//
#include <hip/hip_runtime.h>
#include <hip/hip_bf16.h>

#define B_ 64
#define S_ 512
#define H_ 1024
#define M_ 26
#define E_ 676

typedef short bf16x8 __attribute__((ext_vector_type(8)));
typedef float f32x4 __attribute__((ext_vector_type(4)));

__device__ __forceinline__ void gload16(const void* g, void* l) {
    __builtin_amdgcn_global_load_lds((const __attribute__((address_space(1))) unsigned int*)g,
                                     (__attribute__((address_space(3))) unsigned int*)l,
                                     16, 0, 0);
}

// fast tanh: 1 - 2/(exp(2x)+1); exact at +-inf, ~1e-6 rel err (v_exp + v_rcp)
__device__ __forceinline__ float tanh_fast(float x) {
    float e = __expf(2.0f * x);
    return 1.0f - 2.0f * __builtin_amdgcn_rcpf(e + 1.0f);
}

// ---------- prep: build Wt (3072 x 1024, bf16) = transposed [Wnd ; W1+W3 ; W2-W3] ----------
__global__ void k_prep(const float* __restrict__ Wnd, const float* __restrict__ Wed,
                       __hip_bfloat16* __restrict__ Wt) {
    __shared__ float T[32][33];
    int bx = blockIdx.x, by = blockIdx.y, s = blockIdx.z;
    int t = threadIdx.x;
    int c = t & 31, r0 = t >> 5;
    const int HH = H_ * H_;
#pragma unroll
    for (int i = 0; i < 4; ++i) {
        int r = r0 + 8 * i;                       // k within tile
        size_t k = by * 32 + r, n = bx * 32 + c;
        float v;
        if (s == 0)      v = Wnd[k * H_ + n];
        else if (s == 1) v = Wed[k * H_ + n] + Wed[2 * HH + k * H_ + n];
        else             v = Wed[HH + k * H_ + n] - Wed[2 * HH + k * H_ + n];
        T[r][c] = v;
    }
    __syncthreads();
#pragma unroll
    for (int i = 0; i < 4; ++i) {
        int rr = r0 + 8 * i;                      // n within tile
        Wt[(size_t)(s * H_ + bx * 32 + rr) * H_ + by * 32 + c] = __float2bfloat16(T[c][rr]);
    }
}

// ---------- init: naf=bnaf, cdh=bcd, count, edge-invalid constant ----------
__global__ void k_init(const float* __restrict__ bnaf, const float* __restrict__ bcd,
                       float* __restrict__ naf, float* __restrict__ cdh,
                       const int* __restrict__ off, int* __restrict__ count,
                       const float* __restrict__ bed, const float* __restrict__ Weo,
                       const float* __restrict__ beo, float* __restrict__ econ) {
    __shared__ float s0[256], s1[256];
    int bx = blockIdx.x;
    if (bx < 256) {
        int i = bx * 256 + threadIdx.x;
        naf[i] = bnaf[i & (H_ - 1)];
    } else if (bx < 512) {
        int i = (bx - 256) * 256 + threadIdx.x;
        cdh[i] = bcd[i & (H_ - 1)];
    } else if (bx == 512) {
        if (threadIdx.x < 64) {
            int b = threadIdx.x;
            int c = 0;
            for (int m = 0; m < M_ - 1; ++m) c += (off[b * (M_ - 1) + m] > 0) ? 1 : 0;
            count[b] = c;
        }
    } else {
        // invalid-edge constant logits: tanh(b_ed) @ W_eo + b_eo
        int tid = threadIdx.x;
        float a0 = 0.f, a1 = 0.f;
        for (int h = tid; h < H_; h += 256) {
            float t = tanh_fast(bed[h]);
            a0 += t * Weo[h * 2 + 0];
            a1 += t * Weo[h * 2 + 1];
        }
        s0[tid] = a0; s1[tid] = a1; __syncthreads();
        for (int o = 128; o > 0; o >>= 1) {
            if (tid < o) { s0[tid] += s0[tid + o]; s1[tid] += s1[tid + o]; }
            __syncthreads();
        }
        if (tid == 0) { econ[0] = s0[0] + beo[0]; econ[1] = s1[0] + beo[1]; }
    }
}

// ---------- cls GEMM, split-K tiled: [64 x 1024] @ [1024 x 2048] -> naf|cdh (atomic) ----------
__global__ __launch_bounds__(256) void k_cls2(const float* __restrict__ seq,
                                              const float* __restrict__ Wnaf,
                                              const float* __restrict__ Wcd,
                                              float* __restrict__ naf,
                                              float* __restrict__ cdh) {
    __shared__ float As[16][64];
    __shared__ float Bs[16][64];
    int tid = threadIdx.x;
    int bx = blockIdx.x;
    int kbase = blockIdx.y * 128;
    const float* W;
    float* dst;
    int cbase;
    if (bx < 16) { W = Wnaf; dst = naf; cbase = bx * 64; }
    else         { W = Wcd;  dst = cdh; cbase = (bx - 16) * 64; }
    int tx = tid % 16, ty = tid / 16;
    float c[4][4] = {};
    int la_row = tid / 4;
    int la_k4  = (tid % 4) * 4;
    int lb_k   = tid / 16;
    int lb_c4  = (tid % 16) * 4;
    for (int k0 = 0; k0 < 128; k0 += 16) {
        float4 a = *(const float4*)(seq + (size_t)la_row * S_ * H_ + kbase + k0 + la_k4);
        *(float4*)(&Bs[lb_k][lb_c4]) =
            *(const float4*)(W + (size_t)(kbase + k0 + lb_k) * H_ + cbase + lb_c4);
        As[la_k4 + 0][la_row] = a.x;
        As[la_k4 + 1][la_row] = a.y;
        As[la_k4 + 2][la_row] = a.z;
        As[la_k4 + 3][la_row] = a.w;
        __syncthreads();
#pragma unroll
        for (int kk = 0; kk < 16; ++kk) {
            float4 av = *(const float4*)(&As[kk][ty * 4]);
            float4 bv = *(const float4*)(&Bs[kk][tx * 4]);
            c[0][0] += av.x * bv.x; c[0][1] += av.x * bv.y; c[0][2] += av.x * bv.z; c[0][3] += av.x * bv.w;
            c[1][0] += av.y * bv.x; c[1][1] += av.y * bv.y; c[1][2] += av.y * bv.z; c[1][3] += av.y * bv.w;
            c[2][0] += av.z * bv.x; c[2][1] += av.z * bv.y; c[2][2] += av.z * bv.z; c[2][3] += av.z * bv.w;
            c[3][0] += av.w * bv.x; c[3][1] += av.w * bv.y; c[3][2] += av.w * bv.z; c[3][3] += av.w * bv.w;
        }
        __syncthreads();
    }
#pragma unroll
    for (int i = 0; i < 4; ++i)
#pragma unroll
        for (int j = 0; j < 4; ++j)
            atomicAdd(dst + (size_t)(ty * 4 + i) * H_ + cbase + tx * 4 + j, c[i][j]);
}

// ---------- cls logits ----------
__global__ void k_logits(const float* __restrict__ cdh, const float* __restrict__ Wco,
                         const float* __restrict__ bco, float* __restrict__ out) {
    int b = blockIdx.x, tid = threadIdx.x;
    float a0 = 0.f, a1 = 0.f;
    for (int h = tid; h < H_; h += 256) {
        float t = tanh_fast(cdh[(size_t)b * H_ + h]);
        a0 += t * Wco[h * 2 + 0];
        a1 += t * Wco[h * 2 + 1];
    }
    __shared__ float s0[256], s1[256];
    s0[tid] = a0; s1[tid] = a1; __syncthreads();
    for (int o = 128; o > 0; o >>= 1) {
        if (tid < o) { s0[tid] += s0[tid + o]; s1[tid] += s1[tid + o]; }
        __syncthreads();
    }
    if (tid == 0) { out[b * 2 + 0] = s0[0] + bco[0]; out[b * 2 + 1] = s1[0] + bco[1]; }
}

// ---------- segment sums ----------
__global__ void k_seg(const float* __restrict__ seq, const int* __restrict__ off,
                      float* __restrict__ node_sum) {
    int b = blockIdx.y;
    int chunk = blockIdx.x;
    __shared__ int offs[M_ - 1];
    __shared__ int c_s, offmax_s;
    int tid = threadIdx.x;
    if (tid < M_ - 1) offs[tid] = off[b * (M_ - 1) + tid];
    __syncthreads();
    if (tid == 0) {
        int c = 0;
        while (c < M_ - 1 && offs[c] > 0) c++;
        c_s = c; offmax_s = (c > 0) ? offs[c - 1] : 0;
    }
    __syncthreads();
    int c = c_s, offmax = offmax_s;
    int t0 = chunk * 32;
    int ts = max(t0, 1), te = min(t0 + 31, offmax);
    if (ts > te) return;
    int m = 0;
    while (m < c && offs[m] < ts) m++;
    const float4* sq = (const float4*)(seq + (size_t)b * S_ * H_);
    float4 acc = make_float4(0, 0, 0, 0);
    for (int t = ts; t <= te; ++t) {
        if (offs[m] < t) {
            float* dst = node_sum + ((size_t)(b * M_ + m)) * H_ + tid * 4;
            atomicAdd(dst + 0, acc.x); atomicAdd(dst + 1, acc.y);
            atomicAdd(dst + 2, acc.z); atomicAdd(dst + 3, acc.w);
            acc = make_float4(0, 0, 0, 0);
            while (offs[m] < t) m++;
        }
        float4 v = sq[(size_t)t * (H_ / 4) + tid];
        acc.x += v.x; acc.y += v.y; acc.z += v.z; acc.w += v.w;
    }
    float* dst = node_sum + ((size_t)(b * M_ + m)) * H_ + tid * 4;
    atomicAdd(dst + 0, acc.x); atomicAdd(dst + 1, acc.y);
    atomicAdd(dst + 2, acc.z); atomicAdd(dst + 3, acc.w);
}

// ---------- finalize -> bf16 node matrix ----------
__global__ void k_finalize(const float* __restrict__ sums, const int* __restrict__ off,
                           const int* __restrict__ count, const float* __restrict__ naf,
                           __hip_bfloat16* __restrict__ nodeB) {
    int b = blockIdx.y, m = blockIdx.x, tid = threadIdx.x;
    int cnt = count[b];
    float4 v = make_float4(0, 0, 0, 0);
    const float4* row = (const float4*)(sums + ((size_t)(b * M_ + m)) * H_);
    if (m < M_ - 1) {
        int o = off[b * (M_ - 1) + m];
        if (o > 0) {
            int prev = (m > 0) ? off[b * (M_ - 1) + m - 1] : 0;
            float inv = 1.0f / (float)max(o - prev, 1);
            float4 s = row[tid];
            v = make_float4(s.x * inv, s.y * inv, s.z * inv, s.w * inv);
        }
    }
    if (m == cnt) {
        float4 a = ((const float4*)(naf + (size_t)b * H_))[tid];
        v.x += a.x; v.y += a.y; v.z += a.z; v.w += a.w;
    }
    __hip_bfloat16 __attribute__((aligned(8))) h[4] = {
        __float2bfloat16(v.x), __float2bfloat16(v.y),
        __float2bfloat16(v.z), __float2bfloat16(v.w)};
    *(ushort4*)(nodeB + ((size_t)(b * M_ + m)) * H_ + tid * 4) = *(const ushort4*)h;
}

// ---------- MFMA GEMM: C(1664x3072) = nodeB(1664x1024) @ Wt^T, Wt is (3072x1024) ----------
#define GM 1664
#define GN 3072
#define GK 1024
__global__ __launch_bounds__(256) void k_mfma(const __hip_bfloat16* __restrict__ A,
                                              const __hip_bfloat16* __restrict__ Bt,
                                              float* __restrict__ C) {
    __shared__ __hip_bfloat16 As[128 * 32];
    __shared__ __hip_bfloat16 Bs[128 * 32];
    int tid = threadIdx.x;
    int wid = tid >> 6, ln = tid & 63;
    int row0 = blockIdx.y * 128, col0 = blockIdx.x * 128;
    const __hip_bfloat16* ga = A + (size_t)(row0 + wid * 16 + (ln >> 2)) * GK + (ln & 3) * 8;
    const __hip_bfloat16* gb = Bt + (size_t)(col0 + wid * 16 + (ln >> 2)) * GK + (ln & 3) * 8;
    __hip_bfloat16* lA = As + wid * 512;
    __hip_bfloat16* lB = Bs + wid * 512;
    int mrow = (wid >> 1) * 64, ncol = (wid & 1) * 64;
    int l15 = ln & 15, l4 = ln >> 4;
    f32x4 acc[4][4] = {};
    const __hip_bfloat16* pa = As + (size_t)(mrow + l15) * 32 + l4 * 8;
    const __hip_bfloat16* pb = Bs + (size_t)(ncol + l15) * 32 + l4 * 8;
    for (int k0 = 0; k0 < GK; k0 += 32) {
        gload16(ga, lA);
        gload16(ga + 64 * GK, lA + 2048);
        gload16(gb, lB);
        gload16(gb + 64 * GK, lB + 2048);
        ga += 32; gb += 32;
        __syncthreads();
        bf16x8 af[4], bf[4];
#pragma unroll
        for (int mi = 0; mi < 4; ++mi) af[mi] = *(const bf16x8*)(pa + mi * 16 * 32);
#pragma unroll
        for (int ni = 0; ni < 4; ++ni) bf[ni] = *(const bf16x8*)(pb + ni * 16 * 32);
#pragma unroll
        for (int mi = 0; mi < 4; ++mi)
#pragma unroll
            for (int ni = 0; ni < 4; ++ni)
                acc[mi][ni] = __builtin_amdgcn_mfma_f32_16x16x32_bf16(af[mi], bf[ni],
                                                                      acc[mi][ni], 0, 0, 0);
        __syncthreads();
    }
#pragma unroll
    for (int mi = 0; mi < 4; ++mi)
#pragma unroll
        for (int ni = 0; ni < 4; ++ni) {
            f32x4 v = acc[mi][ni];
            size_t r = row0 + mrow + mi * 16 + l4 * 4;
            size_t cc = col0 + ncol + ni * 16 + l15;
            C[(r + 0) * GN + cc] = v[0];
            C[(r + 1) * GN + cc] = v[1];
            C[(r + 2) * GN + cc] = v[2];
            C[(r + 3) * GN + cc] = v[3];
        }
}

// ---------- node logits: tanh(C[:, :1024] + b_nd) @ W_no + b_no, wave per row ----------
__global__ void k_node_logits(const float* __restrict__ Cm, const float* __restrict__ bnd,
                              const float* __restrict__ Wno, const float* __restrict__ bno,
                              float* __restrict__ out) {
    int r = blockIdx.x * 4 + (threadIdx.x >> 6);
    int lane = threadIdx.x & 63;
    const float4* src = (const float4*)(Cm + (size_t)r * GN);
    float a0 = 0.f, a1 = 0.f;
#pragma unroll
    for (int it = 0; it < 4; ++it) {
        int h = lane * 4 + it * 256;
        float4 s = src[lane + it * 64];
        float4 bb = *(const float4*)(bnd + h);
        float t0 = tanh_fast(s.x + bb.x), t1 = tanh_fast(s.y + bb.y);
        float t2 = tanh_fast(s.z + bb.z), t3 = tanh_fast(s.w + bb.w);
        a0 += t0 * Wno[h * 2 + 0] + t1 * Wno[h * 2 + 2] + t2 * Wno[h * 2 + 4] + t3 * Wno[h * 2 + 6];
        a1 += t0 * Wno[h * 2 + 1] + t1 * Wno[h * 2 + 3] + t2 * Wno[h * 2 + 5] + t3 * Wno[h * 2 + 7];
    }
    for (int o = 32; o > 0; o >>= 1) { a0 += __shfl_down(a0, o); a1 += __shfl_down(a1, o); }
    if (lane == 0) { out[(size_t)r * 2 + 0] = a0 + bno[0]; out[(size_t)r * 2 + 1] = a1 + bno[1]; }
}

// ---------- edge logits: valid-only tanh, reg-cached bed/Weo, const for invalid ----------
__global__ __launch_bounds__(256) void k_edge(const float* __restrict__ Cm,
                                              const int* __restrict__ count,
                                              const float* __restrict__ bed,
                                              const float* __restrict__ Weo,
                                              const float* __restrict__ beo,
                                              const float* __restrict__ econ,
                                              float* __restrict__ out) {
    int b = blockIdx.y;
    int wid = threadIdx.x >> 6, lane = threadIdx.x & 63;
    int wg = blockIdx.x * 4 + wid;                 // 0..63, strides over edges
    int n = count[b] + 1;
    int n2 = n * n;
    float4 bed4[4], w04[4], w14[4];
#pragma unroll
    for (int it = 0; it < 4; ++it) {
        int h = lane * 4 + it * 256;
        bed4[it] = *(const float4*)(bed + h);
        w04[it] = make_float4(Weo[h * 2 + 0], Weo[h * 2 + 2], Weo[h * 2 + 4], Weo[h * 2 + 6]);
        w14[it] = make_float4(Weo[h * 2 + 1], Weo[h * 2 + 3], Weo[h * 2 + 5], Weo[h * 2 + 7]);
    }
    float e0 = econ[0], e1 = econ[1];
    float b0 = beo[0], b1 = beo[1];
    for (int k = wg; k < E_; k += 64) {
        float* dst = out + ((size_t)b * E_ + k) * 2;
        if (k >= n2) {                              // wave-uniform
            if (lane == 0) { dst[0] = e0; dst[1] = e1; }
            continue;
        }
        int i = k / n, j = k - i * n;
        const float4* U4 = (const float4*)(Cm + (size_t)(b * M_ + j) * GN + H_);
        const float4* V4 = (const float4*)(Cm + (size_t)(b * M_ + i) * GN + 2 * H_);
        float a0 = 0.f, a1 = 0.f;
#pragma unroll
        for (int it = 0; it < 4; ++it) {
            float4 u = U4[lane + it * 64];
            float4 v = V4[lane + it * 64];
            float t0 = tanh_fast(u.x + v.x + bed4[it].x);
            float t1 = tanh_fast(u.y + v.y + bed4[it].y);
            float t2 = tanh_fast(u.z + v.z + bed4[it].z);
            float t3 = tanh_fast(u.w + v.w + bed4[it].w);
            a0 += t0 * w04[it].x + t1 * w04[it].y + t2 * w04[it].z + t3 * w04[it].w;
            a1 += t0 * w14[it].x + t1 * w14[it].y + t2 * w14[it].z + t3 * w14[it].w;
        }
        for (int o = 32; o > 0; o >>= 1) { a0 += __shfl_down(a0, o); a1 += __shfl_down(a1, o); }
        if (lane == 0) { dst[0] = a0 + b0; dst[1] = a1 + b1; }
    }
}

extern "C" void kernel_launch(void* const* d_in, const int* in_sizes, int n_in,
                              void* d_out, int out_size, void* d_ws, size_t ws_size,
                              hipStream_t stream) {
    const float* seq  = (const float*)d_in[0];
    const int*   off  = (const int*)d_in[1];
    const float* Wnaf = (const float*)d_in[4];  const float* bnaf = (const float*)d_in[5];
    const float* Wcd  = (const float*)d_in[6];  const float* bcd  = (const float*)d_in[7];
    const float* Wco  = (const float*)d_in[8];  const float* bco  = (const float*)d_in[9];
    const float* Wnd  = (const float*)d_in[10]; const float* bnd  = (const float*)d_in[11];
    const float* Wno  = (const float*)d_in[12]; const float* bno  = (const float*)d_in[13];
    const float* Wed  = (const float*)d_in[14]; const float* bed  = (const float*)d_in[15];
    const float* Weo  = (const float*)d_in[16]; const float* beo  = (const float*)d_in[17];
    float* out = (float*)d_out;

    float* ws = (float*)d_ws;
    size_t p = 0;
    float* nodeS = ws + p;  p += (size_t)B_ * M_ * H_;
    float* naf   = ws + p;  p += (size_t)B_ * H_;
    float* cdh   = ws + p;  p += (size_t)B_ * H_;
    __hip_bfloat16* nodeB = (__hip_bfloat16*)(ws + p); p += (size_t)B_ * M_ * H_ / 2;
    __hip_bfloat16* Wt    = (__hip_bfloat16*)(ws + p); p += (size_t)3 * H_ * H_ / 2;
    float* Cbuf  = ws + p;  p += (size_t)B_ * M_ * 3 * H_;
    int*   cnt   = (int*)(ws + p); p += 64;
    float* econ  = ws + p;  p += 2;

    hipMemsetAsync(nodeS, 0, (size_t)B_ * M_ * H_ * sizeof(float), stream);

    k_prep<<<dim3(32, 32, 3), 256, 0, stream>>>(Wnd, Wed, Wt);
    k_init<<<dim3(514), 256, 0, stream>>>(bnaf, bcd, naf, cdh, off, cnt, bed, Weo, beo, econ);
    k_cls2<<<dim3(32, 8), 256, 0, stream>>>(seq, Wnaf, Wcd, naf, cdh);
    k_logits<<<B_, 256, 0, stream>>>(cdh, Wco, bco, out);
    k_seg<<<dim3(16, B_), 256, 0, stream>>>(seq, off, nodeS);
    k_finalize<<<dim3(M_, B_), 256, 0, stream>>>(nodeS, off, cnt, naf, nodeB);
    k_mfma<<<dim3(GN / 128, GM / 128), 256, 0, stream>>>(nodeB, Wt, Cbuf);
    k_node_logits<<<(B_ * M_) / 4, 256, 0, stream>>>(Cbuf, bnd, Wno, bno, out + B_ * 2);
    k_edge<<<dim3(16, B_), 256, 0, stream>>>(Cbuf, cnt, bed, Weo, beo, econ,
                                             out + B_ * 2 + B_ * M_ * 2);
}

// Round 5
// 311.119 us; speedup vs baseline: 2.1337x; 1.1075x over previous
//
#include <hip/hip_runtime.h>
#include <hip/hip_bf16.h>

#define B_ 64
#define S_ 512
#define H_ 1024
#define M_ 26
#define E_ 676

typedef short bf16x8 __attribute__((ext_vector_type(8)));
typedef float f32x4 __attribute__((ext_vector_type(4)));

__device__ __forceinline__ void gload16(const void* g, void* l) {
    __builtin_amdgcn_global_load_lds((const __attribute__((address_space(1))) unsigned int*)g,
                                     (__attribute__((address_space(3))) unsigned int*)l,
                                     16, 0, 0);
}

// fast tanh: 1 - 2/(exp(2x)+1)
__device__ __forceinline__ float tanh_fast(float x) {
    float e = __expf(2.0f * x);
    return 1.0f - 2.0f * __builtin_amdgcn_rcpf(e + 1.0f);
}

// ================= STAGE 1: prep | count+econ | cls GEMM | segment sums =================
// block partition: [0,3072) prep, 3072 count, 3073 econ, [3074,3330) cls, [3330,4354) seg
__global__ __launch_bounds__(256) void k_stage1(
    const float* __restrict__ seq, const int* __restrict__ off,
    const float* __restrict__ Wnaf, const float* __restrict__ Wcd,
    const float* __restrict__ Wnd, const float* __restrict__ Wed,
    const float* __restrict__ bed, const float* __restrict__ Weo,
    const float* __restrict__ beo,
    __hip_bfloat16* __restrict__ Wt, int* __restrict__ count,
    float* __restrict__ econ, float* __restrict__ naf, float* __restrict__ cdh,
    float* __restrict__ node_sum) {
    __shared__ float smem[2048];
    int bid = blockIdx.x;
    int tid = threadIdx.x;

    if (bid < 3072) {
        // ---- prep: Wt (3072 x 1024 bf16) = transposed [Wnd ; W1+W3 ; W2-W3] ----
        float (*T)[33] = (float(*)[33])smem;
        int s = bid >> 10, rem = bid & 1023;
        int bx = rem & 31, by = rem >> 5;
        int c = tid & 31, r0 = tid >> 5;
        const int HH = H_ * H_;
#pragma unroll
        for (int i = 0; i < 4; ++i) {
            int r = r0 + 8 * i;
            size_t k = by * 32 + r, n = bx * 32 + c;
            float v;
            if (s == 0)      v = Wnd[k * H_ + n];
            else if (s == 1) v = Wed[k * H_ + n] + Wed[2 * HH + k * H_ + n];
            else             v = Wed[HH + k * H_ + n] - Wed[2 * HH + k * H_ + n];
            T[r][c] = v;
        }
        __syncthreads();
#pragma unroll
        for (int i = 0; i < 4; ++i) {
            int rr = r0 + 8 * i;
            Wt[(size_t)(s * H_ + bx * 32 + rr) * H_ + by * 32 + c] = __float2bfloat16(T[c][rr]);
        }
    } else if (bid == 3072) {
        // ---- count ----
        if (tid < 64) {
            int b = tid;
            int c = 0;
            for (int m = 0; m < M_ - 1; ++m) c += (off[b * (M_ - 1) + m] > 0) ? 1 : 0;
            count[b] = c;
        }
    } else if (bid == 3073) {
        // ---- invalid-edge constant logits: tanh(b_ed) @ W_eo + b_eo ----
        float* s0 = smem; float* s1 = smem + 256;
        float a0 = 0.f, a1 = 0.f;
        for (int h = tid; h < H_; h += 256) {
            float t = tanh_fast(bed[h]);
            a0 += t * Weo[h * 2 + 0];
            a1 += t * Weo[h * 2 + 1];
        }
        s0[tid] = a0; s1[tid] = a1; __syncthreads();
        for (int o = 128; o > 0; o >>= 1) {
            if (tid < o) { s0[tid] += s0[tid + o]; s1[tid] += s1[tid + o]; }
            __syncthreads();
        }
        if (tid == 0) { econ[0] = s0[0] + beo[0]; econ[1] = s1[0] + beo[1]; }
    } else if (bid < 3330) {
        // ---- cls GEMM split-K: accumulate cls@W into ZEROED naf|cdh (bias added later) ----
        float (*As)[64] = (float(*)[64])smem;           // [16][64]
        float (*Bs)[64] = (float(*)[64])(smem + 1024);  // [16][64]
        int e = bid - 3074;
        int bx = e & 31;
        int kbase = (e >> 5) * 128;
        const float* W;
        float* dst;
        int cbase;
        if (bx < 16) { W = Wnaf; dst = naf; cbase = bx * 64; }
        else         { W = Wcd;  dst = cdh; cbase = (bx - 16) * 64; }
        int tx = tid % 16, ty = tid / 16;
        float c[4][4] = {};
        int la_row = tid / 4;
        int la_k4  = (tid % 4) * 4;
        int lb_k   = tid / 16;
        int lb_c4  = (tid % 16) * 4;
        for (int k0 = 0; k0 < 128; k0 += 16) {
            float4 a = *(const float4*)(seq + (size_t)la_row * S_ * H_ + kbase + k0 + la_k4);
            *(float4*)(&Bs[lb_k][lb_c4]) =
                *(const float4*)(W + (size_t)(kbase + k0 + lb_k) * H_ + cbase + lb_c4);
            As[la_k4 + 0][la_row] = a.x;
            As[la_k4 + 1][la_row] = a.y;
            As[la_k4 + 2][la_row] = a.z;
            As[la_k4 + 3][la_row] = a.w;
            __syncthreads();
#pragma unroll
            for (int kk = 0; kk < 16; ++kk) {
                float4 av = *(const float4*)(&As[kk][ty * 4]);
                float4 bv = *(const float4*)(&Bs[kk][tx * 4]);
                c[0][0] += av.x * bv.x; c[0][1] += av.x * bv.y; c[0][2] += av.x * bv.z; c[0][3] += av.x * bv.w;
                c[1][0] += av.y * bv.x; c[1][1] += av.y * bv.y; c[1][2] += av.y * bv.z; c[1][3] += av.y * bv.w;
                c[2][0] += av.z * bv.x; c[2][1] += av.z * bv.y; c[2][2] += av.z * bv.z; c[2][3] += av.z * bv.w;
                c[3][0] += av.w * bv.x; c[3][1] += av.w * bv.y; c[3][2] += av.w * bv.z; c[3][3] += av.w * bv.w;
            }
            __syncthreads();
        }
#pragma unroll
        for (int i = 0; i < 4; ++i)
#pragma unroll
            for (int j = 0; j < 4; ++j)
                atomicAdd(dst + (size_t)(ty * 4 + i) * H_ + cbase + tx * 4 + j, c[i][j]);
    } else {
        // ---- segment sums ----
        int e = bid - 3330;
        int chunk = e & 15, b = e >> 4;
        int* offs = (int*)smem;                 // [25]
        int* cs = (int*)smem + 28;              // c_s, offmax_s
        if (tid < M_ - 1) offs[tid] = off[b * (M_ - 1) + tid];
        __syncthreads();
        if (tid == 0) {
            int c = 0;
            while (c < M_ - 1 && offs[c] > 0) c++;
            cs[0] = c; cs[1] = (c > 0) ? offs[c - 1] : 0;
        }
        __syncthreads();
        int c = cs[0], offmax = cs[1];
        int t0 = chunk * 32;
        int ts = max(t0, 1), te = min(t0 + 31, offmax);
        if (ts > te) return;
        int m = 0;
        while (m < c && offs[m] < ts) m++;
        const float4* sq = (const float4*)(seq + (size_t)b * S_ * H_);
        float4 acc = make_float4(0, 0, 0, 0);
        for (int t = ts; t <= te; ++t) {
            if (offs[m] < t) {
                float* dst = node_sum + ((size_t)(b * M_ + m)) * H_ + tid * 4;
                atomicAdd(dst + 0, acc.x); atomicAdd(dst + 1, acc.y);
                atomicAdd(dst + 2, acc.z); atomicAdd(dst + 3, acc.w);
                acc = make_float4(0, 0, 0, 0);
                while (offs[m] < t) m++;
            }
            float4 v = sq[(size_t)t * (H_ / 4) + tid];
            acc.x += v.x; acc.y += v.y; acc.z += v.z; acc.w += v.w;
        }
        float* dst = node_sum + ((size_t)(b * M_ + m)) * H_ + tid * 4;
        atomicAdd(dst + 0, acc.x); atomicAdd(dst + 1, acc.y);
        atomicAdd(dst + 2, acc.z); atomicAdd(dst + 3, acc.w);
    }
}

// ================= STAGE 2: finalize -> bf16 node matrix | cls logits =================
// blocks [0,1664) finalize (m = idx%26, b = idx/26); [1664,1728) logits (b = idx-1664)
__global__ __launch_bounds__(256) void k_stage2(
    const float* __restrict__ sums, const int* __restrict__ off,
    const int* __restrict__ count, const float* __restrict__ naf,
    const float* __restrict__ bnaf, __hip_bfloat16* __restrict__ nodeB,
    const float* __restrict__ cdh, const float* __restrict__ bcd,
    const float* __restrict__ Wco, const float* __restrict__ bco,
    float* __restrict__ out) {
    __shared__ float smem[512];
    int bid = blockIdx.x;
    int tid = threadIdx.x;
    if (bid < 1664) {
        int b = bid / 26, m = bid - b * 26;
        int cnt = count[b];
        float4 v = make_float4(0, 0, 0, 0);
        const float4* row = (const float4*)(sums + ((size_t)(b * M_ + m)) * H_);
        if (m < M_ - 1) {
            int o = off[b * (M_ - 1) + m];
            if (o > 0) {
                int prev = (m > 0) ? off[b * (M_ - 1) + m - 1] : 0;
                float inv = 1.0f / (float)max(o - prev, 1);
                float4 s = row[tid];
                v = make_float4(s.x * inv, s.y * inv, s.z * inv, s.w * inv);
            }
        }
        if (m == cnt) {
            float4 a = ((const float4*)(naf + (size_t)b * H_))[tid];
            float4 bb = ((const float4*)bnaf)[tid];
            v.x += a.x + bb.x; v.y += a.y + bb.y; v.z += a.z + bb.z; v.w += a.w + bb.w;
        }
        __hip_bfloat16 __attribute__((aligned(8))) h[4] = {
            __float2bfloat16(v.x), __float2bfloat16(v.y),
            __float2bfloat16(v.z), __float2bfloat16(v.w)};
        *(ushort4*)(nodeB + ((size_t)(b * M_ + m)) * H_ + tid * 4) = *(const ushort4*)h;
    } else {
        int b = bid - 1664;
        float* s0 = smem; float* s1 = smem + 256;
        float a0 = 0.f, a1 = 0.f;
        for (int h = tid; h < H_; h += 256) {
            float t = tanh_fast(cdh[(size_t)b * H_ + h] + bcd[h]);
            a0 += t * Wco[h * 2 + 0];
            a1 += t * Wco[h * 2 + 1];
        }
        s0[tid] = a0; s1[tid] = a1; __syncthreads();
        for (int o = 128; o > 0; o >>= 1) {
            if (tid < o) { s0[tid] += s0[tid + o]; s1[tid] += s1[tid + o]; }
            __syncthreads();
        }
        if (tid == 0) { out[b * 2 + 0] = s0[0] + bco[0]; out[b * 2 + 1] = s1[0] + bco[1]; }
    }
}

// ================= STAGE 3: MFMA GEMM C(1664x3072) = nodeB @ Wt^T =================
#define GM 1664
#define GN 3072
#define GK 1024
__global__ __launch_bounds__(256) void k_mfma(const __hip_bfloat16* __restrict__ A,
                                              const __hip_bfloat16* __restrict__ Bt,
                                              float* __restrict__ C) {
    __shared__ __hip_bfloat16 As[128 * 32];
    __shared__ __hip_bfloat16 Bs[128 * 32];
    int tid = threadIdx.x;
    int wid = tid >> 6, ln = tid & 63;
    int row0 = blockIdx.y * 128, col0 = blockIdx.x * 128;
    const __hip_bfloat16* ga = A + (size_t)(row0 + wid * 16 + (ln >> 2)) * GK + (ln & 3) * 8;
    const __hip_bfloat16* gb = Bt + (size_t)(col0 + wid * 16 + (ln >> 2)) * GK + (ln & 3) * 8;
    __hip_bfloat16* lA = As + wid * 512;
    __hip_bfloat16* lB = Bs + wid * 512;
    int mrow = (wid >> 1) * 64, ncol = (wid & 1) * 64;
    int l15 = ln & 15, l4 = ln >> 4;
    f32x4 acc[4][4] = {};
    const __hip_bfloat16* pa = As + (size_t)(mrow + l15) * 32 + l4 * 8;
    const __hip_bfloat16* pb = Bs + (size_t)(ncol + l15) * 32 + l4 * 8;
    for (int k0 = 0; k0 < GK; k0 += 32) {
        gload16(ga, lA);
        gload16(ga + 64 * GK, lA + 2048);
        gload16(gb, lB);
        gload16(gb + 64 * GK, lB + 2048);
        ga += 32; gb += 32;
        __syncthreads();
        bf16x8 af[4], bf[4];
#pragma unroll
        for (int mi = 0; mi < 4; ++mi) af[mi] = *(const bf16x8*)(pa + mi * 16 * 32);
#pragma unroll
        for (int ni = 0; ni < 4; ++ni) bf[ni] = *(const bf16x8*)(pb + ni * 16 * 32);
#pragma unroll
        for (int mi = 0; mi < 4; ++mi)
#pragma unroll
            for (int ni = 0; ni < 4; ++ni)
                acc[mi][ni] = __builtin_amdgcn_mfma_f32_16x16x32_bf16(af[mi], bf[ni],
                                                                      acc[mi][ni], 0, 0, 0);
        __syncthreads();
    }
#pragma unroll
    for (int mi = 0; mi < 4; ++mi)
#pragma unroll
        for (int ni = 0; ni < 4; ++ni) {
            f32x4 v = acc[mi][ni];
            size_t r = row0 + mrow + mi * 16 + l4 * 4;
            size_t cc = col0 + ncol + ni * 16 + l15;
            C[(r + 0) * GN + cc] = v[0];
            C[(r + 1) * GN + cc] = v[1];
            C[(r + 2) * GN + cc] = v[2];
            C[(r + 3) * GN + cc] = v[3];
        }
}

// ================= STAGE 4: node logits | edge logits =================
// blocks [0,416) node (4 rows each); [416,1440) edge (bx = e&15, b = e>>4)
__global__ __launch_bounds__(256) void k_stage4(
    const float* __restrict__ Cm, const int* __restrict__ count,
    const float* __restrict__ bnd, const float* __restrict__ Wno,
    const float* __restrict__ bno, const float* __restrict__ bed,
    const float* __restrict__ Weo, const float* __restrict__ beo,
    const float* __restrict__ econ, float* __restrict__ out_n,
    float* __restrict__ out_e) {
    int bid = blockIdx.x;
    int wid = threadIdx.x >> 6, lane = threadIdx.x & 63;
    if (bid < 416) {
        int r = bid * 4 + wid;
        const float4* src = (const float4*)(Cm + (size_t)r * GN);
        float a0 = 0.f, a1 = 0.f;
#pragma unroll
        for (int it = 0; it < 4; ++it) {
            int h = lane * 4 + it * 256;
            float4 s = src[lane + it * 64];
            float4 bb = *(const float4*)(bnd + h);
            float t0 = tanh_fast(s.x + bb.x), t1 = tanh_fast(s.y + bb.y);
            float t2 = tanh_fast(s.z + bb.z), t3 = tanh_fast(s.w + bb.w);
            a0 += t0 * Wno[h * 2 + 0] + t1 * Wno[h * 2 + 2] + t2 * Wno[h * 2 + 4] + t3 * Wno[h * 2 + 6];
            a1 += t0 * Wno[h * 2 + 1] + t1 * Wno[h * 2 + 3] + t2 * Wno[h * 2 + 5] + t3 * Wno[h * 2 + 7];
        }
        for (int o = 32; o > 0; o >>= 1) { a0 += __shfl_down(a0, o); a1 += __shfl_down(a1, o); }
        if (lane == 0) { out_n[(size_t)r * 2 + 0] = a0 + bno[0]; out_n[(size_t)r * 2 + 1] = a1 + bno[1]; }
    } else {
        int e = bid - 416;
        int b = e >> 4;
        int wg = (e & 15) * 4 + wid;
        int n = count[b] + 1;
        int n2 = n * n;
        float4 bed4[4], w04[4], w14[4];
#pragma unroll
        for (int it = 0; it < 4; ++it) {
            int h = lane * 4 + it * 256;
            bed4[it] = *(const float4*)(bed + h);
            w04[it] = make_float4(Weo[h * 2 + 0], Weo[h * 2 + 2], Weo[h * 2 + 4], Weo[h * 2 + 6]);
            w14[it] = make_float4(Weo[h * 2 + 1], Weo[h * 2 + 3], Weo[h * 2 + 5], Weo[h * 2 + 7]);
        }
        float e0 = econ[0], e1 = econ[1];
        float b0 = beo[0], b1 = beo[1];
        for (int k = wg; k < E_; k += 64) {
            float* dst = out_e + ((size_t)b * E_ + k) * 2;
            if (k >= n2) {
                if (lane == 0) { dst[0] = e0; dst[1] = e1; }
                continue;
            }
            int i = k / n, j = k - i * n;
            const float4* U4 = (const float4*)(Cm + (size_t)(b * M_ + j) * GN + H_);
            const float4* V4 = (const float4*)(Cm + (size_t)(b * M_ + i) * GN + 2 * H_);
            float a0 = 0.f, a1 = 0.f;
#pragma unroll
            for (int it = 0; it < 4; ++it) {
                float4 u = U4[lane + it * 64];
                float4 v = V4[lane + it * 64];
                float t0 = tanh_fast(u.x + v.x + bed4[it].x);
                float t1 = tanh_fast(u.y + v.y + bed4[it].y);
                float t2 = tanh_fast(u.z + v.z + bed4[it].z);
                float t3 = tanh_fast(u.w + v.w + bed4[it].w);
                a0 += t0 * w04[it].x + t1 * w04[it].y + t2 * w04[it].z + t3 * w04[it].w;
                a1 += t0 * w14[it].x + t1 * w14[it].y + t2 * w14[it].z + t3 * w14[it].w;
            }
            for (int o = 32; o > 0; o >>= 1) { a0 += __shfl_down(a0, o); a1 += __shfl_down(a1, o); }
            if (lane == 0) { dst[0] = a0 + b0; dst[1] = a1 + b1; }
        }
    }
}

extern "C" void kernel_launch(void* const* d_in, const int* in_sizes, int n_in,
                              void* d_out, int out_size, void* d_ws, size_t ws_size,
                              hipStream_t stream) {
    const float* seq  = (const float*)d_in[0];
    const int*   off  = (const int*)d_in[1];
    const float* Wnaf = (const float*)d_in[4];  const float* bnaf = (const float*)d_in[5];
    const float* Wcd  = (const float*)d_in[6];  const float* bcd  = (const float*)d_in[7];
    const float* Wco  = (const float*)d_in[8];  const float* bco  = (const float*)d_in[9];
    const float* Wnd  = (const float*)d_in[10]; const float* bnd  = (const float*)d_in[11];
    const float* Wno  = (const float*)d_in[12]; const float* bno  = (const float*)d_in[13];
    const float* Wed  = (const float*)d_in[14]; const float* bed  = (const float*)d_in[15];
    const float* Weo  = (const float*)d_in[16]; const float* beo  = (const float*)d_in[17];
    float* out = (float*)d_out;

    float* ws = (float*)d_ws;
    size_t p = 0;
    float* nodeS = ws + p;  p += (size_t)B_ * M_ * H_;           // zeroed
    float* naf   = ws + p;  p += (size_t)B_ * H_;                // zeroed (acc only)
    float* cdh   = ws + p;  p += (size_t)B_ * H_;                // zeroed (acc only)
    __hip_bfloat16* nodeB = (__hip_bfloat16*)(ws + p); p += (size_t)B_ * M_ * H_ / 2;
    __hip_bfloat16* Wt    = (__hip_bfloat16*)(ws + p); p += (size_t)3 * H_ * H_ / 2;
    float* Cbuf  = ws + p;  p += (size_t)B_ * M_ * 3 * H_;
    int*   cnt   = (int*)(ws + p); p += 64;
    float* econ  = ws + p;  p += 2;

    // one memset covers nodeS + naf + cdh (contiguous)
    hipMemsetAsync(nodeS, 0, ((size_t)B_ * M_ * H_ + 2 * (size_t)B_ * H_) * sizeof(float),
                   stream);

    k_stage1<<<dim3(4354), 256, 0, stream>>>(seq, off, Wnaf, Wcd, Wnd, Wed, bed, Weo, beo,
                                             Wt, cnt, econ, naf, cdh, nodeS);
    k_stage2<<<dim3(1728), 256, 0, stream>>>(nodeS, off, cnt, naf, bnaf, nodeB,
                                             cdh, bcd, Wco, bco, out);
    k_mfma<<<dim3(GN / 128, GM / 128), 256, 0, stream>>>(nodeB, Wt, Cbuf);
    k_stage4<<<dim3(1440), 256, 0, stream>>>(Cbuf, cnt, bnd, Wno, bno, bed, Weo, beo, econ,
                                             out + B_ * 2, out + B_ * 2 + B_ * M_ * 2);
}